// Round 7
// baseline (960.175 us; speedup 1.0000x reference)
//
#include <hip/hip_runtime.h>
#include <stdint.h>
#include <stddef.h>

#define FEATDIM 128
#define HIDDIM  256
#define CDIM    64
#define NHOPS   10

typedef __attribute__((ext_vector_type(8))) short bf16x8;
typedef __attribute__((ext_vector_type(4))) float f32x4;
typedef unsigned short u16;

__device__ __forceinline__ u16 f2bf(float f) {
  uint32_t u = __builtin_bit_cast(uint32_t, f);
  u = (u + 0x7fffu + ((u >> 16) & 1u)) >> 16;
  return (u16)u;
}
__device__ __forceinline__ float bf2f(u16 h) {
  uint32_t u = ((uint32_t)h) << 16;
  return __builtin_bit_cast(float, u);
}
__device__ __forceinline__ float bflo(uint32_t u) {
  return __builtin_bit_cast(float, u << 16);
}
__device__ __forceinline__ float bfhi(uint32_t u) {
  return __builtin_bit_cast(float, u & 0xffff0000u);
}

// ---------------- fused weight conversion (all 4 layers, transposed) ----------------
__device__ __forceinline__ void cvt_one(const float* w, u16* wt, int K, int N, int e) {
  int k = e / N, n = e - k * N;
  wt[(size_t)n * K + k] = f2bf(w[e]);
}
__global__ void k_cvt_w(const float* __restrict__ W1, const float* __restrict__ W2,
                        const float* __restrict__ W3, const float* __restrict__ W4,
                        u16* __restrict__ wt1, u16* __restrict__ wt2,
                        u16* __restrict__ wt3, u16* __restrict__ wt4) {
  const int S1 = FEATDIM * HIDDIM;
  const int S2 = S1 + HIDDIM * HIDDIM;
  const int S3 = S2 + HIDDIM * HIDDIM;
  const int S4 = S3 + HIDDIM * CDIM;
  int e = blockIdx.x * blockDim.x + threadIdx.x;
  if (e < S1)      cvt_one(W1, wt1, FEATDIM, HIDDIM, e);
  else if (e < S2) cvt_one(W2, wt2, HIDDIM, HIDDIM, e - S1);
  else if (e < S3) cvt_one(W3, wt3, HIDDIM, HIDDIM, e - S2);
  else if (e < S4) cvt_one(W4, wt4, HIDDIM, CDIM,  e - S3);
}

// ---------------- bf16 MFMA GEMM, BN = 256 (full hidden), 8 waves ----------------
template<int K, bool RESID, bool CVT>
__global__ __launch_bounds__(512) void k_gemm_bn(const void* __restrict__ Av, const u16* __restrict__ WT,
                                                 const float* __restrict__ bias, const float* __restrict__ pa_ptr,
                                                 u16* __restrict__ outb, int M) {
  __shared__ alignas(16) u16 Alds[128 * 32];
  __shared__ alignas(16) u16 Blds[256 * 32];
  const int t = threadIdx.x;
  const int w = t >> 6, l = t & 63;
  const int wr = w >> 2, wc = w & 3;
  const int lr = l & 15, lk = l >> 4;
  const int m0 = blockIdx.x * 128;
  const u16* A = (const u16*)Av;
  const float* Af = (const float*)Av;

  f32x4 acc[4][4];
#pragma unroll
  for (int a = 0; a < 4; ++a)
#pragma unroll
    for (int b = 0; b < 4; ++b)
#pragma unroll
      for (int i = 0; i < 4; ++i) acc[a][b][i] = 0.f;

  for (int k0 = 0; k0 < K; k0 += 32) {
    {
      int row = t >> 2, ks = t & 3;
      int gm = m0 + row; if (gm >= M) gm = M - 1;
      bf16x8 v;
      if constexpr (CVT) {
        const float4* p = (const float4*)(Af + (size_t)gm * K + k0 + ks * 8);
        float4 a0 = p[0], a1 = p[1];
        v[0] = (short)f2bf(a0.x); v[1] = (short)f2bf(a0.y);
        v[2] = (short)f2bf(a0.z); v[3] = (short)f2bf(a0.w);
        v[4] = (short)f2bf(a1.x); v[5] = (short)f2bf(a1.y);
        v[6] = (short)f2bf(a1.z); v[7] = (short)f2bf(a1.w);
      } else {
        v = *(const bf16x8*)(A + (size_t)gm * K + k0 + ks * 8);
      }
      int wks = ks ^ ((row >> 1) & 3);
      *(bf16x8*)&Alds[row * 32 + wks * 8] = v;
    }
#pragma unroll
    for (int s = 0; s < 2; ++s) {
      int slot = t + s * 512;
      int row = slot >> 2, ks = slot & 3;
      bf16x8 v = *(const bf16x8*)(WT + (size_t)row * K + k0 + ks * 8);
      int wks = ks ^ ((row >> 1) & 3);
      *(bf16x8*)&Blds[row * 32 + wks * 8] = v;
    }
    __syncthreads();

    bf16x8 fa[4], fb[4];
#pragma unroll
    for (int mr = 0; mr < 4; ++mr) {
      int row = wr * 64 + mr * 16 + lr;
      int ks = lk ^ ((row >> 1) & 3);
      fa[mr] = *(const bf16x8*)&Alds[row * 32 + ks * 8];
    }
#pragma unroll
    for (int nt = 0; nt < 4; ++nt) {
      int r = wc * 64 + nt * 16 + lr;
      int ks = lk ^ ((r >> 1) & 3);
      fb[nt] = *(const bf16x8*)&Blds[r * 32 + ks * 8];
    }
#pragma unroll
    for (int mr = 0; mr < 4; ++mr)
#pragma unroll
      for (int nt = 0; nt < 4; ++nt)
        acc[mr][nt] = __builtin_amdgcn_mfma_f32_16x16x32_bf16(fa[mr], fb[nt], acc[mr][nt], 0, 0, 0);
    __syncthreads();
  }

  const float pa = pa_ptr[0];
#pragma unroll
  for (int mr = 0; mr < 4; ++mr) {
#pragma unroll
    for (int nt = 0; nt < 4; ++nt) {
#pragma unroll
      for (int i = 0; i < 4; ++i) {
        int row = m0 + wr * 64 + mr * 16 + lk * 4 + i;
        int col = wc * 64 + nt * 16 + lr;
        if (row < M) {
          float v = acc[mr][nt][i] + bias[col];
          if constexpr (RESID) v += bf2f(A[(size_t)row * K + col]);
          v = (v >= 0.f) ? v : pa * v;
          outb[(size_t)row * 256 + col] = f2bf(v);
        }
      }
    }
  }
}

// layer-4 GEMM: K=256 -> N=64
__global__ __launch_bounds__(256) void k_gemm_c(const u16* __restrict__ A, const u16* __restrict__ WT,
                                                const float* __restrict__ bias, u16* __restrict__ outb, int M) {
  __shared__ alignas(16) u16 Alds[128 * 32];
  __shared__ alignas(16) u16 Blds[64 * 32];
  const int t = threadIdx.x;
  const int w = t >> 6, l = t & 63;
  const int lr = l & 15, lk = l >> 4;
  const int m0 = blockIdx.x * 128;
  const int K = 256;

  f32x4 acc[2][4];
#pragma unroll
  for (int a = 0; a < 2; ++a)
#pragma unroll
    for (int b = 0; b < 4; ++b)
#pragma unroll
      for (int i = 0; i < 4; ++i) acc[a][b][i] = 0.f;

  for (int k0 = 0; k0 < K; k0 += 32) {
#pragma unroll
    for (int s = 0; s < 2; ++s) {
      int slot = t + s * 256;
      int row = slot >> 2, ks = slot & 3;
      int gm = m0 + row; if (gm >= M) gm = M - 1;
      bf16x8 v = *(const bf16x8*)(A + (size_t)gm * K + k0 + ks * 8);
      int wks = ks ^ ((row >> 1) & 3);
      *(bf16x8*)&Alds[row * 32 + wks * 8] = v;
    }
    {
      int row = t >> 2, ks = t & 3;
      bf16x8 v = *(const bf16x8*)(WT + (size_t)row * K + k0 + ks * 8);
      int wks = ks ^ ((row >> 1) & 3);
      *(bf16x8*)&Blds[row * 32 + wks * 8] = v;
    }
    __syncthreads();

    bf16x8 fa[2], fb[4];
#pragma unroll
    for (int mr = 0; mr < 2; ++mr) {
      int row = w * 32 + mr * 16 + lr;
      int ks = lk ^ ((row >> 1) & 3);
      fa[mr] = *(const bf16x8*)&Alds[row * 32 + ks * 8];
    }
#pragma unroll
    for (int nt = 0; nt < 4; ++nt) {
      int r = nt * 16 + lr;
      int ks = lk ^ ((r >> 1) & 3);
      fb[nt] = *(const bf16x8*)&Blds[r * 32 + ks * 8];
    }
#pragma unroll
    for (int mr = 0; mr < 2; ++mr)
#pragma unroll
      for (int nt = 0; nt < 4; ++nt)
        acc[mr][nt] = __builtin_amdgcn_mfma_f32_16x16x32_bf16(fa[mr], fb[nt], acc[mr][nt], 0, 0, 0);
    __syncthreads();
  }

#pragma unroll
  for (int mr = 0; mr < 2; ++mr) {
#pragma unroll
    for (int nt = 0; nt < 4; ++nt) {
#pragma unroll
      for (int i = 0; i < 4; ++i) {
        int row = m0 + w * 32 + mr * 16 + lk * 4 + i;
        int col = nt * 16 + lr;
        if (row < M) {
          float v = acc[mr][nt][i] + bias[col];
          outb[(size_t)row * CDIM + col] = f2bf(v);
        }
      }
    }
  }
}

// ---------------- CSR build ----------------
__global__ void k_hist(const int* __restrict__ dst, int* __restrict__ cnt, u16* __restrict__ rank, int E) {
  int e = blockIdx.x * blockDim.x + threadIdx.x;
  if (e < E) rank[e] = (u16)atomicAdd(&cnt[dst[e]], 1);
}

__global__ void k_scan1(const int* __restrict__ cnt, int* __restrict__ scn, int* __restrict__ bsum, int n) {
  __shared__ int s[256];
  int i = blockIdx.x * 256 + threadIdx.x;
  int v = (i < n) ? cnt[i] : 0;
  s[threadIdx.x] = v;
  __syncthreads();
  for (int off = 1; off < 256; off <<= 1) {
    int tv = (threadIdx.x >= off) ? s[threadIdx.x - off] : 0;
    __syncthreads();
    s[threadIdx.x] += tv;
    __syncthreads();
  }
  if (i < n) scn[i] = s[threadIdx.x];
  if (threadIdx.x == 255) bsum[blockIdx.x] = s[255];
}

__global__ void k_scan2(int* __restrict__ bsum, int B) {
  __shared__ int s[512];
  int v = (threadIdx.x < B) ? bsum[threadIdx.x] : 0;
  s[threadIdx.x] = v;
  __syncthreads();
  for (int off = 1; off < 512; off <<= 1) {
    int tv = (threadIdx.x >= off) ? s[threadIdx.x - off] : 0;
    __syncthreads();
    s[threadIdx.x] += tv;
    __syncthreads();
  }
  if (threadIdx.x < B) bsum[threadIdx.x] = s[threadIdx.x];
}

__global__ void k_scan3(const int* __restrict__ scn, const int* __restrict__ bsum, int* __restrict__ row_ptr, int n) {
  int i = blockIdx.x * 256 + threadIdx.x;
  if (i < n) {
    int off = (blockIdx.x > 0) ? bsum[blockIdx.x - 1] : 0;
    row_ptr[i + 1] = scn[i] + off;
  }
  if (i == 0) row_ptr[0] = 0;
}

__global__ void k_scatter(const int* __restrict__ src, const int* __restrict__ dst, const float* __restrict__ nrm,
                          const int* __restrict__ row_ptr, const u16* __restrict__ rank,
                          int2* __restrict__ ed, int E) {
  int e = blockIdx.x * blockDim.x + threadIdx.x;
  if (e >= E) return;
  int d = dst[e];
  int pos = row_ptr[d] + (int)rank[e];
  ed[pos] = make_int2(src[e], __builtin_bit_cast(int, nrm[e]));
}

// ---------------- propagation ----------------
// hop: wave per node; lanes 0-31 process even-pair edges, 32-63 odd; lane = channel pair.
// Edge reads are uniform-per-half-wave loads (HW broadcast); no shuffles.
__global__ void k_hop2(const u16* __restrict__ hc, const int* __restrict__ row_ptr,
                       const int2* __restrict__ ed, u16* __restrict__ hn, int N) {
  int n = blockIdx.x * 4 + (threadIdx.x >> 6);
  int l = threadIdx.x & 63;
  int half = l >> 5;
  int cl = l & 31;
  if (n >= N) return;
  int beg = row_ptr[n], end = row_ptr[n + 1];

  const uint32_t* h32 = (const uint32_t*)hc;
  float ax = 0.f, ay = 0.f;
  int j = beg;
  for (; j + 8 <= end; j += 8) {
    int2 e0 = ed[j + 0 + half];
    int2 e1 = ed[j + 2 + half];
    int2 e2 = ed[j + 4 + half];
    int2 e3 = ed[j + 6 + half];
    uint32_t u0 = h32[(size_t)e0.x * 32 + cl];
    uint32_t u1 = h32[(size_t)e1.x * 32 + cl];
    uint32_t u2 = h32[(size_t)e2.x * 32 + cl];
    uint32_t u3 = h32[(size_t)e3.x * 32 + cl];
    float w0 = __builtin_bit_cast(float, e0.y);
    float w1 = __builtin_bit_cast(float, e1.y);
    float w2 = __builtin_bit_cast(float, e2.y);
    float w3 = __builtin_bit_cast(float, e3.y);
    ax += w0 * bflo(u0); ay += w0 * bfhi(u0);
    ax += w1 * bflo(u1); ay += w1 * bfhi(u1);
    ax += w2 * bflo(u2); ay += w2 * bfhi(u2);
    ax += w3 * bflo(u3); ay += w3 * bfhi(u3);
  }
  for (; j + 2 <= end; j += 2) {
    int2 e = ed[j + half];
    uint32_t u = h32[(size_t)e.x * 32 + cl];
    float w = __builtin_bit_cast(float, e.y);
    ax += w * bflo(u); ay += w * bfhi(u);
  }
  if (j < end && half == 0) {  // odd leftover edge: half 0 only
    int2 e = ed[j];
    uint32_t u = h32[(size_t)e.x * 32 + cl];
    float w = __builtin_bit_cast(float, e.y);
    ax += w * bflo(u); ay += w * bfhi(u);
  }

  ax += __shfl_xor(ax, 32);
  ay += __shfl_xor(ay, 32);
  if (half == 0) {
    uint32_t o = ((uint32_t)f2bf(ay) << 16) | (uint32_t)f2bf(ax);
    ((uint32_t*)hn)[(size_t)n * 32 + cl] = o;
  }
}

// final: half-wave per node; all 11 hop dots reduced concurrently (ILP butterfly)
__global__ __launch_bounds__(256) void k_final(const u16* __restrict__ H, const float* __restrict__ pw,
                                               const float* __restrict__ pb, float* __restrict__ out, int N) {
  int n = blockIdx.x * 8 + (threadIdx.x >> 5);
  int cl = threadIdx.x & 31;
  if (n >= N) return;
  const uint32_t* h32 = (const uint32_t*)H;
  float pwx = pw[2 * cl], pwy = pw[2 * cl + 1];
  float pbv = pb[0];
  size_t stride = (size_t)N * 32;

  float vx[NHOPS + 1], vy[NHOPS + 1], p[NHOPS + 1];
#pragma unroll
  for (int k = 0; k <= NHOPS; ++k) {
    uint32_t u = h32[(size_t)k * stride + (size_t)n * 32 + cl];
    vx[k] = bflo(u); vy[k] = bfhi(u);
    p[k] = vx[k] * pwx + vy[k] * pwy;
  }
  // concurrent butterfly over 32 lanes for all 11 dots
#pragma unroll
  for (int off = 16; off > 0; off >>= 1) {
#pragma unroll
    for (int k = 0; k <= NHOPS; ++k) p[k] += __shfl_xor(p[k], off);
  }
  float accx = 0.f, accy = 0.f;
#pragma unroll
  for (int k = 0; k <= NHOPS; ++k) {
    float sc = 1.f / (1.f + __expf(-(p[k] + pbv)));
    accx += sc * vx[k];
    accy += sc * vy[k];
  }
  float m = fmaxf(accx, accy);
#pragma unroll
  for (int off = 16; off > 0; off >>= 1) m = fmaxf(m, __shfl_xor(m, off));
  float ex = __expf(accx - m), ey = __expf(accy - m);
  float s = ex + ey;
#pragma unroll
  for (int off = 16; off > 0; off >>= 1) s += __shfl_xor(s, off);
  float ls = __logf(s);
  float2 o = make_float2(accx - m - ls, accy - m - ls);
  *(float2*)&out[(size_t)n * CDIM + 2 * cl] = o;
}

// ---------------- launch ----------------
extern "C" void kernel_launch(void* const* d_in, const int* in_sizes, int n_in,
                              void* d_out, int out_size, void* d_ws, size_t ws_size,
                              hipStream_t stream) {
  const float* x   = (const float*)d_in[0];
  const int*   ei  = (const int*)d_in[1];
  const float* nrm = (const float*)d_in[2];
  const float* W1  = (const float*)d_in[3];
  const float* b1  = (const float*)d_in[4];
  const float* W2  = (const float*)d_in[5];
  const float* b2  = (const float*)d_in[6];
  const float* W3  = (const float*)d_in[7];
  const float* b3  = (const float*)d_in[8];
  const float* W4  = (const float*)d_in[9];
  const float* b4  = (const float*)d_in[10];
  const float* pa  = (const float*)d_in[11];
  const float* pw  = (const float*)d_in[12];
  const float* pb  = (const float*)d_in[13];
  float* out = (float*)d_out;

  const int M = in_sizes[0] / FEATDIM;
  const int E = in_sizes[1] / 2;
  const int* srcI = ei;
  const int* dstI = ei + E;

  // ---- workspace layout (aliased; ~155 MB) ----
  char* ws = (char*)d_ws;
  const size_t hs = ((size_t)M * CDIM * 2 + 255) & ~(size_t)255;
  size_t o = 11 * hs;
  auto alloc = [&](size_t bytes) { size_t r = o; o += (bytes + 255) & ~(size_t)255; return r; };
  size_t oW1 = alloc((size_t)FEATDIM * HIDDIM * 2);
  size_t oW2 = alloc((size_t)HIDDIM * HIDDIM * 2);
  size_t oW3 = alloc((size_t)HIDDIM * HIDDIM * 2);
  size_t oW4 = alloc((size_t)HIDDIM * CDIM * 2);
  size_t oRP = alloc((size_t)(M + 1) * 4);
  size_t oBS = alloc(4096);
  size_t oED = alloc((size_t)E * 8);

  u16*  H    = (u16*)ws;
  u16*  zb   = H;                              // H[0]
  u16*  hA   = (u16*)(ws + 1 * hs);            // H[1..4]
  u16*  hB   = (u16*)(ws + 5 * hs);            // H[5..8]
  int*  cnt  = (int*)(ws + 9 * hs);            // dead after CSR build
  int*  scn  = (int*)(ws + 9 * hs + (((size_t)M * 4 + 255) & ~(size_t)255));
  u16*  rank = (u16*)(ws + 9 * hs + 2 * (((size_t)M * 4 + 255) & ~(size_t)255));
  u16*  wt1  = (u16*)(ws + oW1);
  u16*  wt2  = (u16*)(ws + oW2);
  u16*  wt3  = (u16*)(ws + oW3);
  u16*  wt4  = (u16*)(ws + oW4);
  int*  rowp = (int*)(ws + oRP);
  int*  bsum = (int*)(ws + oBS);
  int2* ed   = (int2*)(ws + oED);

  {
    const int tot = FEATDIM * HIDDIM + 2 * HIDDIM * HIDDIM + HIDDIM * CDIM;
    k_cvt_w<<<(tot + 255) / 256, 256, 0, stream>>>(W1, W2, W3, W4, wt1, wt2, wt3, wt4);
  }

  // CSR build
  hipMemsetAsync(cnt, 0, (size_t)M * 4, stream);
  k_hist<<<(E + 255) / 256, 256, 0, stream>>>(dstI, cnt, rank, E);
  int nb = (M + 255) / 256;
  k_scan1<<<nb, 256, 0, stream>>>(cnt, scn, bsum, M);
  k_scan2<<<1, 512, 0, stream>>>(bsum, nb);
  k_scan3<<<nb, 256, 0, stream>>>(scn, bsum, rowp, M);
  k_scatter<<<(E + 255) / 256, 256, 0, stream>>>(srcI, dstI, nrm, rowp, rank, ed, E);

  // MLP
  int gB = (M + 127) / 128;
  k_gemm_bn<FEATDIM, false, true ><<<gB, 512, 0, stream>>>(x,  wt1, b1, pa, hA, M);
  k_gemm_bn<HIDDIM,  true,  false><<<gB, 512, 0, stream>>>(hA, wt2, b2, pa, hB, M);
  k_gemm_bn<HIDDIM,  true,  false><<<gB, 512, 0, stream>>>(hB, wt3, b3, pa, hA, M);
  k_gemm_c<<<gB, 256, 0, stream>>>(hA, wt4, b4, zb, M);

  // propagation
  int nblk = (M + 3) / 4;
  size_t hsel = (size_t)M * CDIM;
  for (int k = 0; k < NHOPS; ++k)
    k_hop2<<<nblk, 256, 0, stream>>>(H + (size_t)k * hsel, rowp, ed, H + (size_t)(k + 1) * hsel, M);
  k_final<<<(M + 7) / 8, 256, 0, stream>>>(H, pw, pb, out, M);
}

// Round 9
// 779.770 us; speedup vs baseline: 1.2314x; 1.2314x over previous
//
#include <hip/hip_runtime.h>
#include <stdint.h>
#include <stddef.h>

#define FEATDIM 128
#define HIDDIM  256
#define CDIM    64
#define NHOPS   10

typedef __attribute__((ext_vector_type(8))) short bf16x8;
typedef __attribute__((ext_vector_type(4))) float f32x4;
typedef unsigned short u16;

__device__ __forceinline__ u16 f2bf(float f) {
  uint32_t u = __builtin_bit_cast(uint32_t, f);
  u = (u + 0x7fffu + ((u >> 16) & 1u)) >> 16;
  return (u16)u;
}
__device__ __forceinline__ float bf2f(u16 h) {
  uint32_t u = ((uint32_t)h) << 16;
  return __builtin_bit_cast(float, u);
}
__device__ __forceinline__ float bflo(uint32_t u) {
  return __builtin_bit_cast(float, u << 16);
}
__device__ __forceinline__ float bfhi(uint32_t u) {
  return __builtin_bit_cast(float, u & 0xffff0000u);
}

// ---------------- fused weight conversion (all 4 layers, transposed) ----------------
__device__ __forceinline__ void cvt_one(const float* w, u16* wt, int K, int N, int e) {
  int k = e / N, n = e - k * N;
  wt[(size_t)n * K + k] = f2bf(w[e]);
}
__global__ void k_cvt_w(const float* __restrict__ W1, const float* __restrict__ W2,
                        const float* __restrict__ W3, const float* __restrict__ W4,
                        u16* __restrict__ wt1, u16* __restrict__ wt2,
                        u16* __restrict__ wt3, u16* __restrict__ wt4) {
  const int S1 = FEATDIM * HIDDIM;
  const int S2 = S1 + HIDDIM * HIDDIM;
  const int S3 = S2 + HIDDIM * HIDDIM;
  const int S4 = S3 + HIDDIM * CDIM;
  int e = blockIdx.x * blockDim.x + threadIdx.x;
  if (e < S1)      cvt_one(W1, wt1, FEATDIM, HIDDIM, e);
  else if (e < S2) cvt_one(W2, wt2, HIDDIM, HIDDIM, e - S1);
  else if (e < S3) cvt_one(W3, wt3, HIDDIM, HIDDIM, e - S2);
  else if (e < S4) cvt_one(W4, wt4, HIDDIM, CDIM,  e - S3);
}

// ---------------- bf16 MFMA GEMM, BN = 256 (full hidden), 8 waves ----------------
template<int K, bool RESID, bool CVT>
__global__ __launch_bounds__(512) void k_gemm_bn(const void* __restrict__ Av, const u16* __restrict__ WT,
                                                 const float* __restrict__ bias, const float* __restrict__ pa_ptr,
                                                 u16* __restrict__ outb, int M) {
  __shared__ alignas(16) u16 Alds[128 * 32];
  __shared__ alignas(16) u16 Blds[256 * 32];
  const int t = threadIdx.x;
  const int w = t >> 6, l = t & 63;
  const int wr = w >> 2, wc = w & 3;
  const int lr = l & 15, lk = l >> 4;
  const int m0 = blockIdx.x * 128;
  const u16* A = (const u16*)Av;
  const float* Af = (const float*)Av;

  f32x4 acc[4][4];
#pragma unroll
  for (int a = 0; a < 4; ++a)
#pragma unroll
    for (int b = 0; b < 4; ++b)
#pragma unroll
      for (int i = 0; i < 4; ++i) acc[a][b][i] = 0.f;

  for (int k0 = 0; k0 < K; k0 += 32) {
    {
      int row = t >> 2, ks = t & 3;
      int gm = m0 + row; if (gm >= M) gm = M - 1;
      bf16x8 v;
      if constexpr (CVT) {
        const float4* p = (const float4*)(Af + (size_t)gm * K + k0 + ks * 8);
        float4 a0 = p[0], a1 = p[1];
        v[0] = (short)f2bf(a0.x); v[1] = (short)f2bf(a0.y);
        v[2] = (short)f2bf(a0.z); v[3] = (short)f2bf(a0.w);
        v[4] = (short)f2bf(a1.x); v[5] = (short)f2bf(a1.y);
        v[6] = (short)f2bf(a1.z); v[7] = (short)f2bf(a1.w);
      } else {
        v = *(const bf16x8*)(A + (size_t)gm * K + k0 + ks * 8);
      }
      int wks = ks ^ ((row >> 1) & 3);
      *(bf16x8*)&Alds[row * 32 + wks * 8] = v;
    }
#pragma unroll
    for (int s = 0; s < 2; ++s) {
      int slot = t + s * 512;
      int row = slot >> 2, ks = slot & 3;
      bf16x8 v = *(const bf16x8*)(WT + (size_t)row * K + k0 + ks * 8);
      int wks = ks ^ ((row >> 1) & 3);
      *(bf16x8*)&Blds[row * 32 + wks * 8] = v;
    }
    __syncthreads();

    bf16x8 fa[4], fb[4];
#pragma unroll
    for (int mr = 0; mr < 4; ++mr) {
      int row = wr * 64 + mr * 16 + lr;
      int ks = lk ^ ((row >> 1) & 3);
      fa[mr] = *(const bf16x8*)&Alds[row * 32 + ks * 8];
    }
#pragma unroll
    for (int nt = 0; nt < 4; ++nt) {
      int r = wc * 64 + nt * 16 + lr;
      int ks = lk ^ ((r >> 1) & 3);
      fb[nt] = *(const bf16x8*)&Blds[r * 32 + ks * 8];
    }
#pragma unroll
    for (int mr = 0; mr < 4; ++mr)
#pragma unroll
      for (int nt = 0; nt < 4; ++nt)
        acc[mr][nt] = __builtin_amdgcn_mfma_f32_16x16x32_bf16(fa[mr], fb[nt], acc[mr][nt], 0, 0, 0);
    __syncthreads();
  }

  const float pa = pa_ptr[0];
#pragma unroll
  for (int mr = 0; mr < 4; ++mr) {
#pragma unroll
    for (int nt = 0; nt < 4; ++nt) {
#pragma unroll
      for (int i = 0; i < 4; ++i) {
        int row = m0 + wr * 64 + mr * 16 + lk * 4 + i;
        int col = wc * 64 + nt * 16 + lr;
        if (row < M) {
          float v = acc[mr][nt][i] + bias[col];
          if constexpr (RESID) v += bf2f(A[(size_t)row * K + col]);
          v = (v >= 0.f) ? v : pa * v;
          outb[(size_t)row * 256 + col] = f2bf(v);
        }
      }
    }
  }
}

// layer-4 GEMM: K=256 -> N=64
__global__ __launch_bounds__(256) void k_gemm_c(const u16* __restrict__ A, const u16* __restrict__ WT,
                                                const float* __restrict__ bias, u16* __restrict__ outb, int M) {
  __shared__ alignas(16) u16 Alds[128 * 32];
  __shared__ alignas(16) u16 Blds[64 * 32];
  const int t = threadIdx.x;
  const int w = t >> 6, l = t & 63;
  const int lr = l & 15, lk = l >> 4;
  const int m0 = blockIdx.x * 128;
  const int K = 256;

  f32x4 acc[2][4];
#pragma unroll
  for (int a = 0; a < 2; ++a)
#pragma unroll
    for (int b = 0; b < 4; ++b)
#pragma unroll
      for (int i = 0; i < 4; ++i) acc[a][b][i] = 0.f;

  for (int k0 = 0; k0 < K; k0 += 32) {
#pragma unroll
    for (int s = 0; s < 2; ++s) {
      int slot = t + s * 256;
      int row = slot >> 2, ks = slot & 3;
      int gm = m0 + row; if (gm >= M) gm = M - 1;
      bf16x8 v = *(const bf16x8*)(A + (size_t)gm * K + k0 + ks * 8);
      int wks = ks ^ ((row >> 1) & 3);
      *(bf16x8*)&Alds[row * 32 + wks * 8] = v;
    }
    {
      int row = t >> 2, ks = t & 3;
      bf16x8 v = *(const bf16x8*)(WT + (size_t)row * K + k0 + ks * 8);
      int wks = ks ^ ((row >> 1) & 3);
      *(bf16x8*)&Blds[row * 32 + wks * 8] = v;
    }
    __syncthreads();

    bf16x8 fa[2], fb[4];
#pragma unroll
    for (int mr = 0; mr < 2; ++mr) {
      int row = w * 32 + mr * 16 + lr;
      int ks = lk ^ ((row >> 1) & 3);
      fa[mr] = *(const bf16x8*)&Alds[row * 32 + ks * 8];
    }
#pragma unroll
    for (int nt = 0; nt < 4; ++nt) {
      int r = nt * 16 + lr;
      int ks = lk ^ ((r >> 1) & 3);
      fb[nt] = *(const bf16x8*)&Blds[r * 32 + ks * 8];
    }
#pragma unroll
    for (int mr = 0; mr < 2; ++mr)
#pragma unroll
      for (int nt = 0; nt < 4; ++nt)
        acc[mr][nt] = __builtin_amdgcn_mfma_f32_16x16x32_bf16(fa[mr], fb[nt], acc[mr][nt], 0, 0, 0);
    __syncthreads();
  }

#pragma unroll
  for (int mr = 0; mr < 2; ++mr) {
#pragma unroll
    for (int nt = 0; nt < 4; ++nt) {
#pragma unroll
      for (int i = 0; i < 4; ++i) {
        int row = m0 + w * 32 + mr * 16 + lk * 4 + i;
        int col = nt * 16 + lr;
        if (row < M) {
          float v = acc[mr][nt][i] + bias[col];
          outb[(size_t)row * CDIM + col] = f2bf(v);
        }
      }
    }
  }
}

// ---------------- CSR build ----------------
__global__ void k_hist(const int* __restrict__ dst, int* __restrict__ cnt, u16* __restrict__ rank, int E) {
  int e = blockIdx.x * blockDim.x + threadIdx.x;
  if (e < E) rank[e] = (u16)atomicAdd(&cnt[dst[e]], 1);
}

__global__ void k_scan1(const int* __restrict__ cnt, int* __restrict__ scn, int* __restrict__ bsum, int n) {
  __shared__ int s[256];
  int i = blockIdx.x * 256 + threadIdx.x;
  int v = (i < n) ? cnt[i] : 0;
  s[threadIdx.x] = v;
  __syncthreads();
  for (int off = 1; off < 256; off <<= 1) {
    int tv = (threadIdx.x >= off) ? s[threadIdx.x - off] : 0;
    __syncthreads();
    s[threadIdx.x] += tv;
    __syncthreads();
  }
  if (i < n) scn[i] = s[threadIdx.x];
  if (threadIdx.x == 255) bsum[blockIdx.x] = s[255];
}

__global__ void k_scan2(int* __restrict__ bsum, int B) {
  __shared__ int s[512];
  int v = (threadIdx.x < B) ? bsum[threadIdx.x] : 0;
  s[threadIdx.x] = v;
  __syncthreads();
  for (int off = 1; off < 512; off <<= 1) {
    int tv = (threadIdx.x >= off) ? s[threadIdx.x - off] : 0;
    __syncthreads();
    s[threadIdx.x] += tv;
    __syncthreads();
  }
  if (threadIdx.x < B) bsum[threadIdx.x] = s[threadIdx.x];
}

__global__ void k_scan3(const int* __restrict__ scn, const int* __restrict__ bsum, int* __restrict__ row_ptr, int n) {
  int i = blockIdx.x * 256 + threadIdx.x;
  if (i < n) {
    int off = (blockIdx.x > 0) ? bsum[blockIdx.x - 1] : 0;
    row_ptr[i + 1] = scn[i] + off;
  }
  if (i == 0) row_ptr[0] = 0;
}

__global__ void k_scatter(const int* __restrict__ src, const int* __restrict__ dst, const float* __restrict__ nrm,
                          const int* __restrict__ row_ptr, const u16* __restrict__ rank,
                          int2* __restrict__ ed, int E) {
  int e = blockIdx.x * blockDim.x + threadIdx.x;
  if (e >= E) return;
  int d = dst[e];
  int pos = row_ptr[d] + (int)rank[e];
  ed[pos] = make_int2(src[e], __builtin_bit_cast(int, nrm[e]));
}

// ---------------- propagation ----------------
// hop: wave per node; lane quarter q handles one edge per group; each lane
// gathers uint2 (4 channels), 16 lanes cover the 128B row -> 4 edges per
// gather instruction, 4 gathers in flight (16-edge unroll). Edge metadata
// via lane-prefetch + shfl broadcast (DS ops, not VMEM). Lanes >= deg hold
// zeroed edges so overrun groups contribute w=0 (shfl idx <= 63 always).
__global__ void k_hop2(const u16* __restrict__ hc, const int* __restrict__ row_ptr,
                       const int2* __restrict__ ed, u16* __restrict__ hn, int N) {
  int n = blockIdx.x * 4 + (threadIdx.x >> 6);
  int l = threadIdx.x & 63;
  int q = l >> 4;          // quarter: which edge of the group of 4
  int cl = l & 15;         // 8B chunk index: channels 4cl..4cl+3
  if (n >= N) return;
  int beg = row_ptr[n], end = row_ptr[n + 1];
  int deg = end - beg;

  int2 e0 = make_int2(0, 0);
  int jn = (deg < 64) ? deg : 64;
  if (l < jn) e0 = ed[beg + l];

  const uint2* h64 = (const uint2*)hc;
  float a0 = 0.f, a1 = 0.f, a2 = 0.f, a3 = 0.f;
  for (int j = 0; j < jn; j += 16) {
#pragma unroll
    for (int g = 0; g < 4; ++g) {
      int idx = j + 4 * g + q;              // <= 48+15 = 63
      int s = __shfl(e0.x, idx);
      float w = __builtin_bit_cast(float, __shfl(e0.y, idx));
      uint2 u = h64[(size_t)s * 16 + cl];
      a0 += w * bflo(u.x); a1 += w * bfhi(u.x);
      a2 += w * bflo(u.y); a3 += w * bfhi(u.y);
    }
  }
  // rare overflow (deg > 64): per-quarter edge loads, masked by weight
  for (int i = beg + 64; i < end; i += 4) {
    int ii = i + q;
    bool v = ii < end;
    int2 e = ed[v ? ii : (end - 1)];
    float w = v ? __builtin_bit_cast(float, e.y) : 0.f;
    uint2 u = h64[(size_t)e.x * 16 + cl];
    a0 += w * bflo(u.x); a1 += w * bfhi(u.x);
    a2 += w * bflo(u.y); a3 += w * bfhi(u.y);
  }

  // reduce across the 4 quarters
  a0 += __shfl_xor(a0, 16); a0 += __shfl_xor(a0, 32);
  a1 += __shfl_xor(a1, 16); a1 += __shfl_xor(a1, 32);
  a2 += __shfl_xor(a2, 16); a2 += __shfl_xor(a2, 32);
  a3 += __shfl_xor(a3, 16); a3 += __shfl_xor(a3, 32);
  if (q == 0) {
    uint2 o;
    o.x = ((uint32_t)f2bf(a1) << 16) | (uint32_t)f2bf(a0);
    o.y = ((uint32_t)f2bf(a3) << 16) | (uint32_t)f2bf(a2);
    ((uint2*)hn)[(size_t)n * 16 + cl] = o;
  }
}

// final: half-wave per node; all 11 hop dots reduced concurrently (ILP butterfly)
__global__ __launch_bounds__(256) void k_final(const u16* __restrict__ H, const float* __restrict__ pw,
                                               const float* __restrict__ pb, float* __restrict__ out, int N) {
  int n = blockIdx.x * 8 + (threadIdx.x >> 5);
  int cl = threadIdx.x & 31;
  if (n >= N) return;
  const uint32_t* h32 = (const uint32_t*)H;
  float pwx = pw[2 * cl], pwy = pw[2 * cl + 1];
  float pbv = pb[0];
  size_t stride = (size_t)N * 32;

  float vx[NHOPS + 1], vy[NHOPS + 1], p[NHOPS + 1];
#pragma unroll
  for (int k = 0; k <= NHOPS; ++k) {
    uint32_t u = h32[(size_t)k * stride + (size_t)n * 32 + cl];
    vx[k] = bflo(u); vy[k] = bfhi(u);
    p[k] = vx[k] * pwx + vy[k] * pwy;
  }
#pragma unroll
  for (int off = 16; off > 0; off >>= 1) {
#pragma unroll
    for (int k = 0; k <= NHOPS; ++k) p[k] += __shfl_xor(p[k], off);
  }
  float accx = 0.f, accy = 0.f;
#pragma unroll
  for (int k = 0; k <= NHOPS; ++k) {
    float sc = 1.f / (1.f + __expf(-(p[k] + pbv)));
    accx += sc * vx[k];
    accy += sc * vy[k];
  }
  float m = fmaxf(accx, accy);
#pragma unroll
  for (int off = 16; off > 0; off >>= 1) m = fmaxf(m, __shfl_xor(m, off));
  float ex = __expf(accx - m), ey = __expf(accy - m);
  float s = ex + ey;
#pragma unroll
  for (int off = 16; off > 0; off >>= 1) s += __shfl_xor(s, off);
  float ls = __logf(s);
  float2 o = make_float2(accx - m - ls, accy - m - ls);
  *(float2*)&out[(size_t)n * CDIM + 2 * cl] = o;
}

// ---------------- launch ----------------
extern "C" void kernel_launch(void* const* d_in, const int* in_sizes, int n_in,
                              void* d_out, int out_size, void* d_ws, size_t ws_size,
                              hipStream_t stream) {
  const float* x   = (const float*)d_in[0];
  const int*   ei  = (const int*)d_in[1];
  const float* nrm = (const float*)d_in[2];
  const float* W1  = (const float*)d_in[3];
  const float* b1  = (const float*)d_in[4];
  const float* W2  = (const float*)d_in[5];
  const float* b2  = (const float*)d_in[6];
  const float* W3  = (const float*)d_in[7];
  const float* b3  = (const float*)d_in[8];
  const float* W4  = (const float*)d_in[9];
  const float* b4  = (const float*)d_in[10];
  const float* pa  = (const float*)d_in[11];
  const float* pw  = (const float*)d_in[12];
  const float* pb  = (const float*)d_in[13];
  float* out = (float*)d_out;

  const int M = in_sizes[0] / FEATDIM;
  const int E = in_sizes[1] / 2;
  const int* srcI = ei;
  const int* dstI = ei + E;

  // ---- workspace layout (aliased; ~155 MB) ----
  char* ws = (char*)d_ws;
  const size_t hs = ((size_t)M * CDIM * 2 + 255) & ~(size_t)255;
  size_t o = 11 * hs;
  auto alloc = [&](size_t bytes) { size_t r = o; o += (bytes + 255) & ~(size_t)255; return r; };
  size_t oW1 = alloc((size_t)FEATDIM * HIDDIM * 2);
  size_t oW2 = alloc((size_t)HIDDIM * HIDDIM * 2);
  size_t oW3 = alloc((size_t)HIDDIM * HIDDIM * 2);
  size_t oW4 = alloc((size_t)HIDDIM * CDIM * 2);
  size_t oRP = alloc((size_t)(M + 1) * 4);
  size_t oBS = alloc(4096);
  size_t oED = alloc((size_t)E * 8);

  u16*  H    = (u16*)ws;
  u16*  zb   = H;                              // H[0]
  u16*  hA   = (u16*)(ws + 1 * hs);            // H[1..4]
  u16*  hB   = (u16*)(ws + 5 * hs);            // H[5..8]
  int*  cnt  = (int*)(ws + 9 * hs);            // dead after CSR build
  int*  scn  = (int*)(ws + 9 * hs + (((size_t)M * 4 + 255) & ~(size_t)255));
  u16*  rank = (u16*)(ws + 9 * hs + 2 * (((size_t)M * 4 + 255) & ~(size_t)255));
  u16*  wt1  = (u16*)(ws + oW1);
  u16*  wt2  = (u16*)(ws + oW2);
  u16*  wt3  = (u16*)(ws + oW3);
  u16*  wt4  = (u16*)(ws + oW4);
  int*  rowp = (int*)(ws + oRP);
  int*  bsum = (int*)(ws + oBS);
  int2* ed   = (int2*)(ws + oED);

  {
    const int tot = FEATDIM * HIDDIM + 2 * HIDDIM * HIDDIM + HIDDIM * CDIM;
    k_cvt_w<<<(tot + 255) / 256, 256, 0, stream>>>(W1, W2, W3, W4, wt1, wt2, wt3, wt4);
  }

  // CSR build
  hipMemsetAsync(cnt, 0, (size_t)M * 4, stream);
  k_hist<<<(E + 255) / 256, 256, 0, stream>>>(dstI, cnt, rank, E);
  int nb = (M + 255) / 256;
  k_scan1<<<nb, 256, 0, stream>>>(cnt, scn, bsum, M);
  k_scan2<<<1, 512, 0, stream>>>(bsum, nb);
  k_scan3<<<nb, 256, 0, stream>>>(scn, bsum, rowp, M);
  k_scatter<<<(E + 255) / 256, 256, 0, stream>>>(srcI, dstI, nrm, rowp, rank, ed, E);

  // MLP
  int gB = (M + 127) / 128;
  k_gemm_bn<FEATDIM, false, true ><<<gB, 512, 0, stream>>>(x,  wt1, b1, pa, hA, M);
  k_gemm_bn<HIDDIM,  true,  false><<<gB, 512, 0, stream>>>(hA, wt2, b2, pa, hB, M);
  k_gemm_bn<HIDDIM,  true,  false><<<gB, 512, 0, stream>>>(hB, wt3, b3, pa, hA, M);
  k_gemm_c<<<gB, 256, 0, stream>>>(hA, wt4, b4, zb, M);

  // propagation
  int nblk = (M + 3) / 4;
  size_t hsel = (size_t)M * CDIM;
  for (int k = 0; k < NHOPS; ++k)
    k_hop2<<<nblk, 256, 0, stream>>>(H + (size_t)k * hsel, rowp, ed, H + (size_t)(k + 1) * hsel, M);
  k_final<<<(M + 7) / 8, 256, 0, stream>>>(H, pw, pb, out, M);
}